// Round 5
// baseline (245.744 us; speedup 1.0000x reference)
//
#include <hip/hip_runtime.h>
#include <hip/hip_bf16.h>

// CapsuleLayer dynamic routing. B=64, I=2048, D=16, J=32, K=16, routings=3.
// Known from counters: inputs f32 (probe flag=1), ws >= 142.7 MB (BT=64),
// u_hat bf16 internal (134 MB), absmax margin 4.4x.
// Round-5 changes:
//  - produce: no LDS/barrier; x read via wave-uniform (readfirstlane) global
//    loads; W in 64 VGPRs; 256-thr blocks, 2 i's each.
//  - route: lane owns full j row (16 k, 2x dwordx4); in-lane logit dot;
//    softmax = 5 shfl per 32-lane half; 2 i's per wave-iteration.

#define B_ 64
#define I_ 2048
#define D_ 16
#define J_ 32
#define K_ 16
#define JK 512  // J_*K_

__device__ __forceinline__ float bf2f(unsigned int u) {
    union { unsigned int i; float f; } v;
    v.i = u << 16;
    return v.f;
}

__device__ __forceinline__ unsigned short f2bf(float f) {
    union { float f; unsigned int i; } v;
    v.f = f;
    const unsigned int x = v.i;
    return (unsigned short)((x + 0x7fffu + ((x >> 16) & 1u)) >> 16);  // RNE
}

__device__ __forceinline__ void unpack8(const uint4 r, float* u) {
    u[0] = bf2f(r.x & 0xffffu); u[1] = bf2f(r.x >> 16);
    u[2] = bf2f(r.y & 0xffffu); u[3] = bf2f(r.y >> 16);
    u[4] = bf2f(r.z & 0xffffu); u[5] = bf2f(r.z >> 16);
    u[6] = bf2f(r.w & 0xffffu); u[7] = bf2f(r.w >> 16);
}

// ---------------------------------------------------------------------------
// Dtype probe: flag=1 means f32 inputs/outputs.
// ---------------------------------------------------------------------------
__global__ __launch_bounds__(64)
void caps_probe(const unsigned short* __restrict__ x, int* __restrict__ flag) {
    const int lane = threadIdx.x;
    int wild = 0;
#pragma unroll 8
    for (int t = 0; t < 128; ++t) {
        const unsigned int u = x[(size_t)lane * 128 + t];
        const unsigned int e = (u >> 7) & 0xffu;
        wild += (e >= 0xC0u) ? 1 : 0;
    }
    wild += __shfl_xor(wild, 1, 64);
    wild += __shfl_xor(wild, 2, 64);
    wild += __shfl_xor(wild, 4, 64);
    wild += __shfl_xor(wild, 8, 64);
    wild += __shfl_xor(wild, 16, 64);
    wild += __shfl_xor(wild, 32, 64);
    if (lane == 0) *flag = (wild > 32) ? 1 : 0;
}

// ---------------------------------------------------------------------------
// Producer: grid I_/2 x 256 threads. Subgroup g = tid>>7 handles i = 2*blk+g.
// st = tid&127 -> (j = st>>2, kh = st&3), jk = st*4..st*4+3.
// No LDS: x[b,i,:] is wave-uniform -> broadcast global loads each bl.
// ---------------------------------------------------------------------------
__global__ __launch_bounds__(256)
void caps_produce(const void* __restrict__ xv, const void* __restrict__ Wv,
                  unsigned short* __restrict__ uhat, int b0, int BT,
                  const int* __restrict__ flag) {
    const int tid = threadIdx.x;
    const int g = tid >> 7;    // 0..1 (wave-uniform: tid>>7 constant per wave)
    const int st = tid & 127;
    int i = (blockIdx.x << 1) | g;
    i = __builtin_amdgcn_readfirstlane(i);  // force SGPR -> scalar x loads
    const bool F32 = (*flag != 0);

    // W[i, j, :, kh*4..kh*4+3] -> 64 VGPRs (f32)
    float w[16][4];
    {
        const int j = st >> 2, kh = st & 3;
        if (F32) {
            const float* wp = (const float*)Wv + (size_t)i * (J_ * D_ * K_) +
                              j * (D_ * K_) + kh * 4;
#pragma unroll
            for (int d = 0; d < 16; ++d) {
                const float4 r = *reinterpret_cast<const float4*>(wp + d * K_);
                w[d][0] = r.x; w[d][1] = r.y; w[d][2] = r.z; w[d][3] = r.w;
            }
        } else {
            const unsigned short* wp = (const unsigned short*)Wv +
                                       (size_t)i * (J_ * D_ * K_) +
                                       j * (D_ * K_) + kh * 4;
#pragma unroll
            for (int d = 0; d < 16; ++d) {
                const uint2 r = *reinterpret_cast<const uint2*>(wp + d * K_);
                w[d][0] = bf2f(r.x & 0xffffu); w[d][1] = bf2f(r.x >> 16);
                w[d][2] = bf2f(r.y & 0xffffu); w[d][3] = bf2f(r.y >> 16);
            }
        }
    }

#pragma unroll 4
    for (int bl = 0; bl < BT; ++bl) {
        // x[b0+bl, i, :] — uniform address across the wave
        float xs[16];
        if (F32) {
            const float* xp =
                (const float*)xv + ((size_t)(b0 + bl) * I_ + i) * D_;
            const float4 r0 = reinterpret_cast<const float4*>(xp)[0];
            const float4 r1 = reinterpret_cast<const float4*>(xp)[1];
            const float4 r2 = reinterpret_cast<const float4*>(xp)[2];
            const float4 r3 = reinterpret_cast<const float4*>(xp)[3];
            xs[0] = r0.x; xs[1] = r0.y; xs[2] = r0.z; xs[3] = r0.w;
            xs[4] = r1.x; xs[5] = r1.y; xs[6] = r1.z; xs[7] = r1.w;
            xs[8] = r2.x; xs[9] = r2.y; xs[10] = r2.z; xs[11] = r2.w;
            xs[12] = r3.x; xs[13] = r3.y; xs[14] = r3.z; xs[15] = r3.w;
        } else {
            const unsigned short* xp =
                (const unsigned short*)xv + ((size_t)(b0 + bl) * I_ + i) * D_;
            const uint4 r0 = reinterpret_cast<const uint4*>(xp)[0];
            const uint4 r1 = reinterpret_cast<const uint4*>(xp)[1];
            unpack8(r0, xs);
            unpack8(r1, xs + 8);
        }
        float a[4] = {0.f, 0.f, 0.f, 0.f};
#pragma unroll
        for (int d = 0; d < 16; ++d) {
#pragma unroll
            for (int c = 0; c < 4; ++c) a[c] += xs[d] * w[d][c];
        }
        uint2 pk;
        pk.x = ((unsigned int)f2bf(a[1]) << 16) | f2bf(a[0]);
        pk.y = ((unsigned int)f2bf(a[3]) << 16) | f2bf(a[2]);
        *reinterpret_cast<uint2*>(
            uhat + ((size_t)bl * I_ + i) * JK + st * 4) = pk;
    }
}

// ---------------------------------------------------------------------------
// Routing pass: BT*64 waves (4/block). Wave = (bl, chunk of 32 i).
// lane l: h = l>>5 (i parity), j = l&31 -> owns u_hat[b, i0+2t+h, j, 0..15]
// (32 B = 2x dwordx4). Logit dot fully in-lane; softmax over j = 5 shfl
// within the 32-lane half. Halves combined once after the loop.
// ---------------------------------------------------------------------------
template <bool R0>
__global__ __launch_bounds__(256)
void caps_route(const unsigned short* __restrict__ uhat,
                const float* __restrict__ vsum,
                float* __restrict__ spart, int BT) {
    const int lane = threadIdx.x & 63;
    const int wave = blockIdx.x * 4 + (threadIdx.x >> 6);
    const int bl = wave >> 6;     // 0..BT-1
    const int chunk = wave & 63;  // 0..63
    const int i0 = chunk * 32;
    const int h = lane >> 5;      // i parity
    const int j = lane & 31;

    float v[16];
    if (!R0) {
        const float4* vp =
            reinterpret_cast<const float4*>(vsum + bl * JK + j * 16);
        const float4 a0 = vp[0], a1 = vp[1], a2 = vp[2], a3 = vp[3];
        v[0] = a0.x; v[1] = a0.y; v[2] = a0.z; v[3] = a0.w;
        v[4] = a1.x; v[5] = a1.y; v[6] = a1.z; v[7] = a1.w;
        v[8] = a2.x; v[9] = a2.y; v[10] = a2.z; v[11] = a2.w;
        v[12] = a3.x; v[13] = a3.y; v[14] = a3.z; v[15] = a3.w;
    }

    float acc[16];
#pragma unroll
    for (int k = 0; k < 16; ++k) acc[k] = 0.f;

    const unsigned short* up =
        uhat + ((size_t)bl * I_ + i0 + h) * JK + j * 16;

#pragma unroll 2
    for (int t = 0; t < 16; ++t) {
        const uint4* rp =
            reinterpret_cast<const uint4*>(up + (size_t)t * 2 * JK);
        const uint4 r0 = rp[0], r1 = rp[1];
        float u[16];
        unpack8(r0, u);
        unpack8(r1, u + 8);
        float c;
        if (R0) {
            c = 1.f;  // uniform coupling; 1/32 folded into squash
        } else {
            float p = 0.f;
#pragma unroll
            for (int k = 0; k < 16; ++k) p += u[k] * v[k];
            // |p| bounded (~30): f32 exp safe without max-subtraction
            const float e = __expf(p);
            float S = e;  // softmax denom over 32 j's (within half)
            S += __shfl_xor(S, 1, 64);
            S += __shfl_xor(S, 2, 64);
            S += __shfl_xor(S, 4, 64);
            S += __shfl_xor(S, 8, 64);
            S += __shfl_xor(S, 16, 64);
            c = e / (S + 1e-30f);
        }
#pragma unroll
        for (int k = 0; k < 16; ++k) acc[k] += c * u[k];
    }

    // combine the two i-parity halves (same (b,j,k))
#pragma unroll
    for (int k = 0; k < 16; ++k) acc[k] += __shfl_xor(acc[k], 32, 64);

    if (h == 0) {
        float* sp = spart + ((size_t)chunk * BT + bl) * JK + j * 16;
        float4 o;
#pragma unroll
        for (int q = 0; q < 4; ++q) {
            o.x = acc[q * 4 + 0]; o.y = acc[q * 4 + 1];
            o.z = acc[q * 4 + 2]; o.w = acc[q * 4 + 3];
            reinterpret_cast<float4*>(sp)[q] = o;
        }
    }
}

// ---------------------------------------------------------------------------
// Squash: grid = BT, 512 threads = (j = tid>>4, k = tid&15).
// MODE 0: s *= 1/32 (uniform c), vsum = v.  MODE 1: vsum += v.
// MODE 2: out = v in the dataset dtype.
// ---------------------------------------------------------------------------
template <int MODE>
__global__ __launch_bounds__(512)
void caps_squash(const float* __restrict__ spart, float* __restrict__ vsum,
                 void* __restrict__ out, int b0, int BT,
                 const int* __restrict__ flag) {
    const int bl = blockIdx.x;
    const int jk = threadIdx.x;
    float s = 0.f;
#pragma unroll 8
    for (int p = 0; p < 64; ++p)
        s += spart[((size_t)p * BT + bl) * JK + jk];
    if (MODE == 0) s *= (1.f / 32.f);
    float q = s * s;  // reduce over k (16-lane groups, in-wave)
    q += __shfl_xor(q, 1, 64);
    q += __shfl_xor(q, 2, 64);
    q += __shfl_xor(q, 4, 64);
    q += __shfl_xor(q, 8, 64);
    const float scale = q / ((1.f + q) * sqrtf(q + 1e-7f));
    const float v = scale * s;
    if (MODE == 0)      vsum[bl * JK + jk] = v;
    else if (MODE == 1) vsum[bl * JK + jk] += v;
    else {
        const size_t o = (size_t)(b0 + bl) * JK + jk;
        if (*flag) ((float*)out)[o] = v;
        else       ((unsigned short*)out)[o] = f2bf(v);
    }
}

// ---------------------------------------------------------------------------
extern "C" void kernel_launch(void* const* d_in, const int* in_sizes, int n_in,
                              void* d_out, int out_size, void* d_ws,
                              size_t ws_size, hipStream_t stream) {
    const void* x = d_in[0];  // [B,I,D], f32 (probed on device)
    const void* W = d_in[1];  // [I,J,D,K]
    char* ws = (char*)d_ws;

    int BT = 64;
    auto need = [](int bt) -> size_t {
        return (size_t)bt * I_ * JK * 2      // uhat (bf16)
             + (size_t)64 * bt * JK * 4      // spart
             + (size_t)bt * JK * 4           // vsum
             + 256;                          // flag
    };
    while (BT > 1 && need(BT) > ws_size) BT >>= 1;

    unsigned short* uhat = (unsigned short*)ws;
    float* spart = (float*)(ws + (size_t)BT * I_ * JK * 2);
    float* vsum = spart + (size_t)64 * BT * JK;
    int* flag = (int*)(vsum + (size_t)BT * JK);

    caps_probe<<<1, 64, 0, stream>>>((const unsigned short*)x, flag);

    const int NT = B_ / BT;
    for (int t = 0; t < NT; ++t) {
        const int b0 = t * BT;
        caps_produce<<<I_ / 2, 256, 0, stream>>>(x, W, uhat, b0, BT, flag);

        caps_route<true><<<BT * 16, 256, 0, stream>>>(uhat, vsum, spart, BT);
        caps_squash<0><<<BT, 512, 0, stream>>>(spart, vsum, d_out, b0, BT, flag);

        caps_route<false><<<BT * 16, 256, 0, stream>>>(uhat, vsum, spart, BT);
        caps_squash<1><<<BT, 512, 0, stream>>>(spart, vsum, d_out, b0, BT, flag);

        caps_route<false><<<BT * 16, 256, 0, stream>>>(uhat, vsum, spart, BT);
        caps_squash<2><<<BT, 512, 0, stream>>>(spart, vsum, d_out, b0, BT, flag);
    }
}